// Round 9
// baseline (98.720 us; speedup 1.0000x reference)
//
#include <hip/hip_runtime.h>
#include <math.h>

#define NQ   10
#define NLAY 4
#define BATCH 4096
#define HID  32
#define NM   20   // 2*NQ

typedef float    f2  __attribute__((ext_vector_type(2)));
typedef unsigned u2v __attribute__((ext_vector_type(2)));

// ---------------------------------------------------------------------------
// Compile-time tracking of the CNOT ring as a GF(2) linear map.
// col[l][k] = pair-xor mask between storage indices for layer-l gate on wire k
// row[l][k] = parity mask giving logical bit x_k from storage index
// Storage bit layout (one element per FULL 64-lane wave):
//   s = (lane << 4) | reg
//   bits 9..4 -> lane bits 5..0 (wires 0..5)
//   bits 3..0 -> reg index r in 0..15 (wires 6..9)
// Exchange classes by pair-mask lane bits: bit5 -> one full-wave __shfl_xor
// (ds_bpermute); bit4 -> one ds_swizzle; bits 3..0 -> DPP.
//
// Measured ledger:
//   R5: +1150 VALU instr/wave -> +4.8us  => wall pays VALU issue 1:1.
//   R7 lockstep / R8 sched_barrier ILP   => neutral (structure not the issue).
//   VALUBusy 51% @ 92K cyc/SIMD wall     => ~5.9K VALU instr/wave emitted,
//     vs ~3K ideal => ~2.4K operand-shuffle movs from unfolded mk2() shapes
//     in cmac (the {a0,a0}/{-a1,a1}/{b1,b0} broadcasts VOP3P op_sel can do
//     for free).
// R9 fix: inline-asm v_pk_fma_f32 with explicit op_sel/op_sel_hi -> exactly
// 2 VALU per complex MAC, guaranteed. Coefficients get pre-negated
// companions {-im,+im} (amortized, avoids neg_lo syntax risk).
// Harness model (rounds 2-8): bench_us = kernel_us + ~57 fixed. Kernel 1:1.
// ---------------------------------------------------------------------------
struct Tables {
    unsigned col[NLAY + 1][NQ];
    unsigned row[NLAY + 1][NQ];
};

constexpr Tables make_tables() {
    Tables t{};
    unsigned col[NQ] = {}, row[NQ] = {};
    for (int k = 0; k < NQ; ++k) { col[k] = 1u << (NQ - 1 - k); row[k] = 1u << (NQ - 1 - k); }
    for (int l = 0; l <= NLAY; ++l) {
        for (int k = 0; k < NQ; ++k) { t.col[l][k] = col[k]; t.row[l][k] = row[k]; }
        for (int k = 0; k < NQ; ++k) {            // ring: CNOT(k, (k+1)%NQ)
            int c = k, tg = (k + 1) % NQ;
            col[c] ^= col[tg];
            row[tg] ^= row[c];
        }
    }
    return t;
}

static constexpr Tables TB = make_tables();

struct cpx { float x, y; };
__device__ __forceinline__ cpx cxmul(cpx a, cpx b) {
    return { fmaf(a.x, b.x, -a.y * b.y), fmaf(a.x, b.y, a.y * b.x) };
}

__device__ __forceinline__ f2 mk2(float a, float b) { f2 r; r[0] = a; r[1] = b; return r; }

// ---- complex MAC: acc += a (*) b, exactly 2 VOP3P instructions ------------
// an must hold {-a.im, +a.im} (precomputed once per coefficient).
// P1: lo += a.re*b.re            (op_sel src0 lo, src1 lo)
//     hi += a.re*b.im            (op_sel_hi src0 LO, src1 hi)
// P2: lo += (-a.im)*b.im         (src0=an lo, src1 hi)
//     hi += (+a.im)*b.re         (src0=an hi, src1 lo)
__device__ __forceinline__ f2 cmac2(f2 acc, f2 a, f2 an, f2 b) {
    asm("v_pk_fma_f32 %0, %1, %2, %0 op_sel_hi:[0,1,1]"
        : "+v"(acc) : "v"(a), "v"(b));
    asm("v_pk_fma_f32 %0, %1, %2, %0 op_sel:[0,1,0] op_sel_hi:[1,0,1]"
        : "+v"(acc) : "v"(an), "v"(b));
    return acc;
}

// ---- DPP lane-xor within a 16-lane row (VALU pipe) ------------------------
template<int CTRL>
__device__ __forceinline__ float dppf(float x) {
    return __int_as_float(__builtin_amdgcn_update_dpp(
        0, __float_as_int(x), CTRL, 0xF, 0xF, true));
}

template<unsigned M>
__device__ __forceinline__ float dpplo(float x) {
    static_assert(M < 16u, "dpplo handles masks 0..15");
    if constexpr (M == 0u)       return x;
    else if constexpr (M == 1u)  return dppf<0xB1>(x);                 // quad_perm [1,0,3,2]
    else if constexpr (M == 2u)  return dppf<0x4E>(x);                 // quad_perm [2,3,0,1]
    else if constexpr (M == 3u)  return dppf<0x1B>(x);                 // quad_perm [3,2,1,0]
    else if constexpr (M == 7u)  return dppf<0x141>(x);                // row_half_mirror
    else if constexpr (M == 8u)  return dppf<0x128>(x);                // row_ror:8
    else if constexpr (M == 15u) return dppf<0x140>(x);                // row_mirror
    else if constexpr (M == 4u)  return dppf<0x141>(dppf<0x1B>(x));    // 7^3
    else if constexpr (M == 5u)  return dppf<0x141>(dppf<0x4E>(x));    // 7^2
    else if constexpr (M == 6u)  return dppf<0x141>(dppf<0xB1>(x));    // 7^1
    else if constexpr (M == 9u)  return dppf<0x128>(dppf<0xB1>(x));    // 8^1
    else if constexpr (M == 10u) return dppf<0x128>(dppf<0x4E>(x));    // 8^2
    else if constexpr (M == 11u) return dppf<0x128>(dppf<0x1B>(x));    // 8^3
    else if constexpr (M == 12u) return dppf<0x140>(dppf<0x1B>(x));    // 15^3
    else if constexpr (M == 13u) return dppf<0x140>(dppf<0x4E>(x));    // 15^2
    else                         return dppf<0x140>(dppf<0xB1>(x));    // 14 = 15^1
}

// x + x^16 fold (convention-independent permlane16_swap)
__device__ __forceinline__ float redfold16(float x) {
#if __has_builtin(__builtin_amdgcn_permlane16_swap)
    u2v r = __builtin_amdgcn_permlane16_swap(__float_as_uint(x), __float_as_uint(x), false, false);
    return __uint_as_float(r[0]) + __uint_as_float(r[1]);
#else
    return x + __shfl_xor(x, 16);
#endif
}

// x + x^32 fold (cross-half)
__device__ __forceinline__ float redfold32(float x) {
#if __has_builtin(__builtin_amdgcn_permlane32_swap)
    u2v r = __builtin_amdgcn_permlane32_swap(__float_as_uint(x), __float_as_uint(x), false, false);
    return __uint_as_float(r[0]) + __uint_as_float(r[1]);
#else
    return x + __shfl_xor(x, 32);
#endif
}

// lane-xor by compile-time MASK (MASK <= 63):
// bit 5 present -> one full-wave ds_bpermute via __shfl_xor (addr CSE'd);
// bit 4 present -> ONE ds_swizzle (BitMode xor, covers bits 0..4);
// bits 0..3 only -> DPP on the VALU pipe.
template<unsigned M>
__device__ __forceinline__ float xlane(float x) {
    if constexpr (M == 0u) return x;
    else if constexpr ((M & 32u) != 0u)
        return __shfl_xor(x, (int)M);            // 64-lane bpermute, full 6-bit xor
    else if constexpr ((M & 16u) != 0u)
        return __int_as_float(__builtin_amdgcn_ds_swizzle(
            __float_as_int(x), (int)((M << 10) | 0x1F)));   // xor within 32 lanes
    else return dpplo<M>(x);                                // VALU pipe
}

// ---- one single-qubit gate, 16 amps/lane, fully specialized ---------------
template<int L, int K>
__device__ __forceinline__ void apply_gate(f2 (&st)[16], const float4 (*gm)[2],
                                           const int lane) {
    constexpr unsigned v     = TB.col[L][K];
    constexpr unsigned m     = TB.row[L][K];
    constexpr unsigned vlane = (v >> 4) & 63u;
    constexpr int      vr    = (int)(v & 15u);
    constexpr unsigned mlane = (m >> 4) & 63u;
    constexpr int      mr    = (int)(m & 15u);
    constexpr int      gi    = L * NQ + K;

    int laneP = 0;
    if constexpr (mlane != 0u) laneP = __popc((unsigned)lane & mlane) & 1;
    const float4 A = gm[gi][laneP];
    const f2 ocA = mk2(A.x, A.y), pcA = mk2(A.z, A.w);
    const f2 ocAn = mk2(-A.y, A.y), pcAn = mk2(-A.w, A.w);
    f2 ocB = ocA, pcB = pcA, ocBn = ocAn, pcBn = pcAn;
    if constexpr (mr != 0) {
        const float4 B = gm[gi][laneP ^ 1];
        ocB = mk2(B.x, B.y); pcB = mk2(B.z, B.w);
        ocBn = mk2(-B.y, B.y); pcBn = mk2(-B.w, B.w);
    }

    if constexpr (vlane != 0u) {
        // ---- lane-exchange gate: batch all 32 exchanges, pin, then the
        //      FMA sweep (16 independent 4-deep pk_fma chains).
        f2 pt[16];
        #pragma unroll
        for (int r = 0; r < 16; ++r)
            pt[r] = mk2(xlane<vlane>(st[r ^ vr][0]), xlane<vlane>(st[r ^ vr][1]));
        __builtin_amdgcn_sched_barrier(0);
        #pragma unroll
        for (int r = 0; r < 16; ++r) {
            const int pr = __builtin_popcount((unsigned)(r & mr)) & 1;
            const f2 oc  = pr ? ocB  : ocA;
            const f2 ocn = pr ? ocBn : ocAn;
            const f2 pc  = pr ? pcB  : pcA;
            const f2 pcn = pr ? pcBn : pcAn;
            f2 acc = mk2(0.f, 0.f);
            acc = cmac2(acc, oc, ocn, st[r]);
            acc = cmac2(acc, pc, pcn, pt[r]);
            st[r] = acc;
        }
        return;
    }

    // ---- reg-only gate: pair-local processing (no exchange instructions)
    #pragma unroll
    for (int r = 0; r < 16; ++r) {
        const int r2 = r ^ vr;
        if (r2 < r) continue;
        const f2 p_r  = st[r2];
        const f2 p_r2 = st[r];
        const int pr = __builtin_popcount((unsigned)(r & mr)) & 1;
        {
            const f2 oc  = pr ? ocB  : ocA;
            const f2 ocn = pr ? ocBn : ocAn;
            const f2 pc  = pr ? pcB  : pcA;
            const f2 pcn = pr ? pcBn : pcAn;
            f2 acc = mk2(0.f, 0.f);
            acc = cmac2(acc, oc, ocn, st[r]);
            acc = cmac2(acc, pc, pcn, p_r);
            const int pr2 = __builtin_popcount((unsigned)(r2 & mr)) & 1;
            const f2 oc2  = pr2 ? ocB  : ocA;
            const f2 oc2n = pr2 ? ocBn : ocAn;
            const f2 pc2  = pr2 ? pcB  : pcA;
            const f2 pc2n = pr2 ? pcBn : pcAn;
            f2 acc2 = mk2(0.f, 0.f);
            acc2 = cmac2(acc2, oc2, oc2n, st[r2]);
            acc2 = cmac2(acc2, pc2, pc2n, p_r2);
            st[r2] = acc2;
            st[r] = acc;
        }
    }
}

// One block = 256 threads = 4 waves = 4 batch elements (one per full wave).
// No barriers in the gate loop; grid = BATCH/4 = 1024 blocks.
__global__ __launch_bounds__(256, 4)
void qrh_kernel(
    const float* __restrict__ theta, const float* __restrict__ rotw,
    const float* __restrict__ escale, const float* __restrict__ ebias,
    const float* __restrict__ W1, const float* __restrict__ b1,
    const float* __restrict__ W2, const float* __restrict__ b2,
    float* __restrict__ out)
{
    // per element, per gate: group0=[U00,U01], group1=[U11,U10]
    __shared__ float4 gmat[4 * NLAY * NQ][2];
    __shared__ float4 wtab[4][NQ];   // layer-0 product vectors per element

    const int tid  = threadIdx.x;
    const int lane = tid & 63;
    const int wv   = tid >> 6;
    const int e    = wv;                        // element in block 0..3
    const int b    = blockIdx.x * 4 + e;

    // ---- per-gate 2x2 unitary, thread-parallel over 4*40 = 160 gates ----
    for (int g = tid; g < 4 * NLAY * NQ; g += 256) {
        const int ge = g / (NLAY * NQ);       // element 0..3
        const int gg = g % (NLAY * NQ);
        const int l = gg / NQ, k = gg % NQ;
        const int gb = blockIdx.x * 4 + ge;
        const float th = theta[gb * NQ + k];
        const int e2 = (l * NQ + k) * 2;
        const float t0 = escale[e2 + 0] * th + ebias[e2 + 0];
        const float t1 = escale[e2 + 1] * th + ebias[e2 + 1];
        float sn0, c0, sn1, c1;
        __sincosf(0.5f * t0, &sn0, &c0);
        __sincosf(0.5f * t1, &sn1, &c1);
        // U_enc = RX(t1) RZ(t0)
        const f2 E00 = mk2( c1 * c0,  -c1 * sn0);
        const f2 E01 = mk2( sn1 * sn0, -sn1 * c0);
        const f2 E10 = mk2(-sn1 * sn0, -sn1 * c0);
        const f2 E11 = mk2( c1 * c0,   c1 * sn0);
        const int r3 = (l * NQ + k) * 3;
        const float w0 = rotw[r3 + 0], w1 = rotw[r3 + 1], w2 = rotw[r3 + 2];
        float cw, sw, ca0, sa0, ca1, sa1;
        __sincosf(0.5f * w1, &sw, &cw);
        __sincosf(0.5f * (w0 + w2), &sa0, &ca0);
        __sincosf(0.5f * (w0 - w2), &sa1, &ca1);
        // U_rot = RZ(w2) RY(w1) RZ(w0)
        const f2 R00 = mk2( cw * ca0, -cw * sa0);
        const f2 R01 = mk2(-sw * ca1, -sw * sa1);
        const f2 R10 = mk2( sw * ca1, -sw * sa1);
        const f2 R11 = mk2( cw * ca0,  cw * sa0);
        auto cm = [](f2 a, f2 bb) { return mk2(a[0]*bb[0] - a[1]*bb[1], a[0]*bb[1] + a[1]*bb[0]); };
        const f2 U00 = cm(R00, E00) + cm(R01, E10);
        const f2 U01 = cm(R00, E01) + cm(R01, E11);
        const f2 U10 = cm(R10, E00) + cm(R11, E10);
        const f2 U11 = cm(R10, E01) + cm(R11, E11);
        gmat[g][0] = make_float4(U00[0], U00[1], U01[0], U01[1]);
        gmat[g][1] = make_float4(U11[0], U11[1], U10[0], U10[1]);
        if (l == 0) {
            // layer-0 acts on |+>^10: per-wire 2-vector w = U*(1,1)/sqrt(2)
            const float inv = 0.70710678118654752f;
            const f2 al = (U00 + U01) * inv;
            const f2 be = (U10 + U11) * inv;
            wtab[ge][k] = make_float4(al[0], al[1], be[0], be[1]);
        }
    }
    __syncthreads();

    // ---- layer-0 state = product state: amp(s) = prod_k w_k[s_k] ----------
    // wires 0..5 -> lane bits 5..0, wires 6..9 -> reg bits 3..0
    f2 st[16];
    {
        cpx pre;
        {
            const float4 q = wtab[e][0];
            pre = ((lane >> 5) & 1) ? cpx{q.z, q.w} : cpx{q.x, q.y};
            #pragma unroll
            for (int k = 1; k < 6; ++k) {
                const float4 t = wtab[e][k];
                const cpx w_ = ((lane >> (5 - k)) & 1) ? cpx{t.z, t.w} : cpx{t.x, t.y};
                pre = cxmul(pre, w_);
            }
        }
        const float4 q6 = wtab[e][6], q7 = wtab[e][7];
        const float4 q8 = wtab[e][8], q9 = wtab[e][9];
        const cpx w6[2] = {{q6.x, q6.y}, {q6.z, q6.w}};
        const cpx w7[2] = {{q7.x, q7.y}, {q7.z, q7.w}};
        const cpx w8[2] = {{q8.x, q8.y}, {q8.z, q8.w}};
        const cpx w9[2] = {{q9.x, q9.y}, {q9.z, q9.w}};
        cpx a67[4];
        #pragma unroll
        for (int j = 0; j < 4; ++j)
            a67[j] = cxmul(cxmul(pre, w6[j >> 1]), w7[j & 1]);
        cpx w89[4];
        #pragma unroll
        for (int j = 0; j < 4; ++j)
            w89[j] = cxmul(w8[j >> 1], w9[j & 1]);
        #pragma unroll
        for (int r = 0; r < 16; ++r) {
            const cpx t = cxmul(a67[r >> 2], w89[r & 3]);
            st[r] = mk2(t.x, t.y);
        }
    }

    const float4 (*gm)[2] = &gmat[e * NLAY * NQ];

    #define GATE(L,K) apply_gate<L,K>(st, gm, lane);
    #define LAYER(L) GATE(L,0) GATE(L,1) GATE(L,2) GATE(L,3) GATE(L,4) \
                     GATE(L,5) GATE(L,6) GATE(L,7) GATE(L,8) GATE(L,9)
    LAYER(1)
    LAYER(2)
    LAYER(3)
    #undef LAYER
    #undef GATE

    // ---- measurement: probs then 4-bit FWHT over register index ----
    float w[16];
    #pragma unroll
    for (int r = 0; r < 16; ++r) {
        const f2 sq = st[r] * st[r];
        w[r] = sq[0] + sq[1];
    }
    #pragma unroll
    for (int bit = 1; bit < 16; bit <<= 1) {
        #pragma unroll
        for (int j = 0; j < 16; ++j) {
            if (!(j & bit)) {
                const float a = w[j], c = w[j | bit];
                w[j] = a + c; w[j | bit] = a - c;
            }
        }
    }
    // w[t] = sum_r (-1)^{popc(r&t)} p[r]

    float feats[NM];
    #pragma unroll
    for (int f = 0; f < NM; ++f) {
        const unsigned M = (f < NQ) ? TB.row[NLAY][f]
                                    : (TB.row[NLAY][f - NQ] ^ TB.row[NLAY][(f - NQ + 1) % NQ]);
        const unsigned Mlane = (M >> 4) & 63u;
        const int Mr = (int)(M & 15u);
        const float s = w[Mr];
        const int lsgn = __popc((unsigned)lane & Mlane) & 1;
        feats[f] = lsgn ? -s : s;
    }
    // reduction across all 64 lanes over basis masks {1,2,7,8,16,32}
    #pragma unroll
    for (int f = 0; f < NM; ++f) {
        float v = feats[f];
        v += dppf<0xB1>(v);    // ^1
        v += dppf<0x4E>(v);    // ^2
        v += dppf<0x141>(v);   // ^7
        v += dppf<0x128>(v);   // ^8
        v = redfold16(v);      // ^16
        v = redfold32(v);      // ^32
        feats[f] = v;
    }

    // ---- MLP head: lanes l and l+32 redundantly compute hidden unit l&31;
    //      the full-wave sum double-counts, so scale by 0.5 (exact).
    const int hl = lane & 31;
    float part;
    {
        float acc = b1[hl];
        #pragma unroll
        for (int mm = 0; mm < NM; ++mm) acc = fmaf(feats[mm], W1[hl * NM + mm], acc);
        const float sg = 1.f / (1.f + __expf(-acc));
        part = acc * sg * W2[hl];
    }
    part += dppf<0xB1>(part);
    part += dppf<0x4E>(part);
    part += dppf<0x141>(part);
    part += dppf<0x128>(part);
    part = redfold16(part);
    part = redfold32(part);
    if (lane == 0) out[b] = fmaf(0.5f, part, b2[0]);
}

extern "C" void kernel_launch(void* const* d_in, const int* in_sizes, int n_in,
                              void* d_out, int out_size, void* d_ws, size_t ws_size,
                              hipStream_t stream) {
    (void)in_sizes; (void)n_in; (void)out_size; (void)d_ws; (void)ws_size;
    const float* theta = (const float*)d_in[0];
    const float* rotw  = (const float*)d_in[1];
    const float* esc   = (const float*)d_in[2];
    const float* ebi   = (const float*)d_in[3];
    const float* W1    = (const float*)d_in[4];
    const float* b1    = (const float*)d_in[5];
    const float* W2    = (const float*)d_in[6];
    const float* b2    = (const float*)d_in[7];
    float* out = (float*)d_out;

    qrh_kernel<<<BATCH / 4, 256, 0, stream>>>(theta, rotw, esc, ebi, W1, b1, W2, b2, out);
}

// Round 10
// 95.083 us; speedup vs baseline: 1.0383x; 1.0383x over previous
//
#include <hip/hip_runtime.h>
#include <math.h>

#define NQ   10
#define NLAY 4
#define BATCH 4096
#define HID  32
#define NM   20   // 2*NQ

typedef float    f2  __attribute__((ext_vector_type(2)));
typedef unsigned u2v __attribute__((ext_vector_type(2)));

// ---------------------------------------------------------------------------
// Compile-time tracking of the CNOT ring as a GF(2) linear map.
// col[l][k] = pair-xor mask between storage indices for layer-l gate on wire k
// row[l][k] = parity mask giving logical bit x_k from storage index
// Storage bit layout (one element per FULL 64-lane wave):
//   s = (lane << 4) | reg
//   bits 9..4 -> lane bits 5..0 (wires 0..5)
//   bits 3..0 -> reg index r in 0..15 (wires 6..9)
//
// Measured ledger:
//   R5: exchanges LDS->VALU: +1150 VALU instr/wave -> +4.8us (1:1 issue cost)
//   R7 lockstep barriers / R8 sched_barrier ILP pin: neutral
//   R9 hand-asm pk_fma: +1us (compiler already packs; asm added zero-init movs)
//   VALU pipe 51-59% busy, LDS pipe ~idle (12/30 gates, ~380 ops/wave)
// R10: run R5's experiment in the PROFITABLE direction — move ALL lane
// exchanges onto the idle LDS pipe:
//   vlane 1..31  -> ONE ds_swizzle (BitMode xor of lane bits 0..4), replacing
//                   the 1-2 v_mov_dpp VALU instrs each (−~512 VALU/wave)
//   vlane >= 32  -> ds_bpermute with the address (lane^vlane)<<2 hoisted
//                   ONCE per gate (−~224 VALU/wave vs per-call __shfl_xor)
// Everything else identical to R8 (best bench 95.12; builtin cmac).
// Harness model (rounds 2-9): bench_us = kernel_us + ~57 fixed. Kernel 1:1.
// ---------------------------------------------------------------------------
struct Tables {
    unsigned col[NLAY + 1][NQ];
    unsigned row[NLAY + 1][NQ];
};

constexpr Tables make_tables() {
    Tables t{};
    unsigned col[NQ] = {}, row[NQ] = {};
    for (int k = 0; k < NQ; ++k) { col[k] = 1u << (NQ - 1 - k); row[k] = 1u << (NQ - 1 - k); }
    for (int l = 0; l <= NLAY; ++l) {
        for (int k = 0; k < NQ; ++k) { t.col[l][k] = col[k]; t.row[l][k] = row[k]; }
        for (int k = 0; k < NQ; ++k) {            // ring: CNOT(k, (k+1)%NQ)
            int c = k, tg = (k + 1) % NQ;
            col[c] ^= col[tg];
            row[tg] ^= row[c];
        }
    }
    return t;
}

static constexpr Tables TB = make_tables();

struct cpx { float x, y; };
__device__ __forceinline__ cpx cxmul(cpx a, cpx b) {
    return { fmaf(a.x, b.x, -a.y * b.y), fmaf(a.x, b.y, a.y * b.x) };
}

__device__ __forceinline__ f2 mk2(float a, float b) { f2 r; r[0] = a; r[1] = b; return r; }
__device__ __forceinline__ f2 ffma(f2 a, f2 b, f2 c) { return __builtin_elementwise_fma(a, b, c); }

// acc += a (*) b   complex, interleaved (re,im) per f2 (VOP3P-foldable shapes).
__device__ __forceinline__ f2 cmac(f2 acc, f2 a, f2 b) {
    acc = ffma(mk2(a[0], a[0]), b, acc);
    acc = ffma(mk2(-a[1], a[1]), mk2(b[1], b[0]), acc);
    return acc;
}

// ---- DPP helpers (epilogue reductions only) -------------------------------
template<int CTRL>
__device__ __forceinline__ float dppf(float x) {
    return __int_as_float(__builtin_amdgcn_update_dpp(
        0, __float_as_int(x), CTRL, 0xF, 0xF, true));
}

// x + x^16 fold (convention-independent permlane16_swap)
__device__ __forceinline__ float redfold16(float x) {
#if __has_builtin(__builtin_amdgcn_permlane16_swap)
    u2v r = __builtin_amdgcn_permlane16_swap(__float_as_uint(x), __float_as_uint(x), false, false);
    return __uint_as_float(r[0]) + __uint_as_float(r[1]);
#else
    return x + __shfl_xor(x, 16);
#endif
}

// x + x^32 fold (cross-half)
__device__ __forceinline__ float redfold32(float x) {
#if __has_builtin(__builtin_amdgcn_permlane32_swap)
    u2v r = __builtin_amdgcn_permlane32_swap(__float_as_uint(x), __float_as_uint(x), false, false);
    return __uint_as_float(r[0]) + __uint_as_float(r[1]);
#else
    return x + __shfl_xor(x, 32);
#endif
}

// lane-xor by compile-time MASK (MASK <= 63), ALWAYS on the LDS pipe:
// bit 5 present -> ds_bpermute with hoisted per-gate address bp;
// otherwise     -> ONE ds_swizzle (BitMode xor covers lane bits 0..4).
template<unsigned M>
__device__ __forceinline__ float xlane(float x, int bp) {
    if constexpr (M == 0u) return x;
    else if constexpr ((M & 32u) != 0u)
        return __int_as_float(__builtin_amdgcn_ds_bpermute(bp, __float_as_int(x)));
    else
        return __int_as_float(__builtin_amdgcn_ds_swizzle(
            __float_as_int(x), (int)((M << 10) | 0x1F)));   // xor within 32 lanes
}

// ---- one single-qubit gate, 16 amps/lane, fully specialized ---------------
template<int L, int K>
__device__ __forceinline__ void apply_gate(f2 (&st)[16], const float4 (*gm)[2],
                                           const int lane) {
    constexpr unsigned v     = TB.col[L][K];
    constexpr unsigned m     = TB.row[L][K];
    constexpr unsigned vlane = (v >> 4) & 63u;
    constexpr int      vr    = (int)(v & 15u);
    constexpr unsigned mlane = (m >> 4) & 63u;
    constexpr int      mr    = (int)(m & 15u);
    constexpr int      gi    = L * NQ + K;

    int laneP = 0;
    if constexpr (mlane != 0u) laneP = __popc((unsigned)lane & mlane) & 1;
    const float4 A = gm[gi][laneP];
    const f2 ocA = mk2(A.x, A.y), pcA = mk2(A.z, A.w);
    f2 ocB = ocA, pcB = pcA;
    if constexpr (mr != 0) {
        const float4 B = gm[gi][laneP ^ 1];
        ocB = mk2(B.x, B.y); pcB = mk2(B.z, B.w);
    }

    if constexpr (vlane != 0u) {
        // ---- lane-exchange gate: ONE LDS op per float. Batch all 32
        //      exchanges, pin, then the FMA sweep (16 independent chains).
        int bp = 0;
        if constexpr ((vlane & 32u) != 0u)
            bp = (lane ^ (int)vlane) << 2;     // bpermute addr, once per gate
        f2 pt[16];
        #pragma unroll
        for (int r = 0; r < 16; ++r)
            pt[r] = mk2(xlane<vlane>(st[r ^ vr][0], bp),
                        xlane<vlane>(st[r ^ vr][1], bp));
        __builtin_amdgcn_sched_barrier(0);
        #pragma unroll
        for (int r = 0; r < 16; ++r) {
            const int pr = __builtin_popcount((unsigned)(r & mr)) & 1;
            const f2 oc = pr ? ocB : ocA;
            const f2 pc = pr ? pcB : pcA;
            f2 acc = mk2(0.f, 0.f);
            acc = cmac(acc, oc, st[r]);
            acc = cmac(acc, pc, pt[r]);
            st[r] = acc;
        }
        return;
    }

    // ---- reg-only gate: pair-local processing (no exchange instructions)
    #pragma unroll
    for (int r = 0; r < 16; ++r) {
        const int r2 = r ^ vr;
        if (r2 < r) continue;
        const f2 p_r  = st[r2];
        const f2 p_r2 = st[r];
        const int pr = __builtin_popcount((unsigned)(r & mr)) & 1;
        const f2 oc = pr ? ocB : ocA;
        const f2 pc = pr ? pcB : pcA;
        f2 acc = mk2(0.f, 0.f);
        acc = cmac(acc, oc, st[r]);
        acc = cmac(acc, pc, p_r);
        const int pr2 = __builtin_popcount((unsigned)(r2 & mr)) & 1;
        const f2 oc2 = pr2 ? ocB : ocA;
        const f2 pc2 = pr2 ? pcB : pcA;
        f2 acc2 = mk2(0.f, 0.f);
        acc2 = cmac(acc2, oc2, st[r2]);
        acc2 = cmac(acc2, pc2, p_r2);
        st[r2] = acc2;
        st[r] = acc;
    }
}

// One block = 256 threads = 4 waves = 4 batch elements (one per full wave).
// No barriers in the gate loop; grid = BATCH/4 = 1024 blocks.
__global__ __launch_bounds__(256, 4)
void qrh_kernel(
    const float* __restrict__ theta, const float* __restrict__ rotw,
    const float* __restrict__ escale, const float* __restrict__ ebias,
    const float* __restrict__ W1, const float* __restrict__ b1,
    const float* __restrict__ W2, const float* __restrict__ b2,
    float* __restrict__ out)
{
    // per element, per gate: group0=[U00,U01], group1=[U11,U10]
    __shared__ float4 gmat[4 * NLAY * NQ][2];
    __shared__ float4 wtab[4][NQ];   // layer-0 product vectors per element

    const int tid  = threadIdx.x;
    const int lane = tid & 63;
    const int wv   = tid >> 6;
    const int e    = wv;                        // element in block 0..3
    const int b    = blockIdx.x * 4 + e;

    // ---- per-gate 2x2 unitary, thread-parallel over 4*40 = 160 gates ----
    for (int g = tid; g < 4 * NLAY * NQ; g += 256) {
        const int ge = g / (NLAY * NQ);       // element 0..3
        const int gg = g % (NLAY * NQ);
        const int l = gg / NQ, k = gg % NQ;
        const int gb = blockIdx.x * 4 + ge;
        const float th = theta[gb * NQ + k];
        const int e2 = (l * NQ + k) * 2;
        const float t0 = escale[e2 + 0] * th + ebias[e2 + 0];
        const float t1 = escale[e2 + 1] * th + ebias[e2 + 1];
        float sn0, c0, sn1, c1;
        __sincosf(0.5f * t0, &sn0, &c0);
        __sincosf(0.5f * t1, &sn1, &c1);
        // U_enc = RX(t1) RZ(t0)
        const f2 E00 = mk2( c1 * c0,  -c1 * sn0);
        const f2 E01 = mk2( sn1 * sn0, -sn1 * c0);
        const f2 E10 = mk2(-sn1 * sn0, -sn1 * c0);
        const f2 E11 = mk2( c1 * c0,   c1 * sn0);
        const int r3 = (l * NQ + k) * 3;
        const float w0 = rotw[r3 + 0], w1 = rotw[r3 + 1], w2 = rotw[r3 + 2];
        float cw, sw, ca0, sa0, ca1, sa1;
        __sincosf(0.5f * w1, &sw, &cw);
        __sincosf(0.5f * (w0 + w2), &sa0, &ca0);
        __sincosf(0.5f * (w0 - w2), &sa1, &ca1);
        // U_rot = RZ(w2) RY(w1) RZ(w0)
        const f2 R00 = mk2( cw * ca0, -cw * sa0);
        const f2 R01 = mk2(-sw * ca1, -sw * sa1);
        const f2 R10 = mk2( sw * ca1, -sw * sa1);
        const f2 R11 = mk2( cw * ca0,  cw * sa0);
        auto cm = [](f2 a, f2 bb) { return mk2(a[0]*bb[0] - a[1]*bb[1], a[0]*bb[1] + a[1]*bb[0]); };
        const f2 U00 = cm(R00, E00) + cm(R01, E10);
        const f2 U01 = cm(R00, E01) + cm(R01, E11);
        const f2 U10 = cm(R10, E00) + cm(R11, E10);
        const f2 U11 = cm(R10, E01) + cm(R11, E11);
        gmat[g][0] = make_float4(U00[0], U00[1], U01[0], U01[1]);
        gmat[g][1] = make_float4(U11[0], U11[1], U10[0], U10[1]);
        if (l == 0) {
            // layer-0 acts on |+>^10: per-wire 2-vector w = U*(1,1)/sqrt(2)
            const float inv = 0.70710678118654752f;
            const f2 al = (U00 + U01) * inv;
            const f2 be = (U10 + U11) * inv;
            wtab[ge][k] = make_float4(al[0], al[1], be[0], be[1]);
        }
    }
    __syncthreads();

    // ---- layer-0 state = product state: amp(s) = prod_k w_k[s_k] ----------
    // wires 0..5 -> lane bits 5..0, wires 6..9 -> reg bits 3..0
    f2 st[16];
    {
        cpx pre;
        {
            const float4 q = wtab[e][0];
            pre = ((lane >> 5) & 1) ? cpx{q.z, q.w} : cpx{q.x, q.y};
            #pragma unroll
            for (int k = 1; k < 6; ++k) {
                const float4 t = wtab[e][k];
                const cpx w_ = ((lane >> (5 - k)) & 1) ? cpx{t.z, t.w} : cpx{t.x, t.y};
                pre = cxmul(pre, w_);
            }
        }
        const float4 q6 = wtab[e][6], q7 = wtab[e][7];
        const float4 q8 = wtab[e][8], q9 = wtab[e][9];
        const cpx w6[2] = {{q6.x, q6.y}, {q6.z, q6.w}};
        const cpx w7[2] = {{q7.x, q7.y}, {q7.z, q7.w}};
        const cpx w8[2] = {{q8.x, q8.y}, {q8.z, q8.w}};
        const cpx w9[2] = {{q9.x, q9.y}, {q9.z, q9.w}};
        cpx a67[4];
        #pragma unroll
        for (int j = 0; j < 4; ++j)
            a67[j] = cxmul(cxmul(pre, w6[j >> 1]), w7[j & 1]);
        cpx w89[4];
        #pragma unroll
        for (int j = 0; j < 4; ++j)
            w89[j] = cxmul(w8[j >> 1], w9[j & 1]);
        #pragma unroll
        for (int r = 0; r < 16; ++r) {
            const cpx t = cxmul(a67[r >> 2], w89[r & 3]);
            st[r] = mk2(t.x, t.y);
        }
    }

    const float4 (*gm)[2] = &gmat[e * NLAY * NQ];

    #define GATE(L,K) apply_gate<L,K>(st, gm, lane);
    #define LAYER(L) GATE(L,0) GATE(L,1) GATE(L,2) GATE(L,3) GATE(L,4) \
                     GATE(L,5) GATE(L,6) GATE(L,7) GATE(L,8) GATE(L,9)
    LAYER(1)
    LAYER(2)
    LAYER(3)
    #undef LAYER
    #undef GATE

    // ---- measurement: probs then 4-bit FWHT over register index ----
    float w[16];
    #pragma unroll
    for (int r = 0; r < 16; ++r) {
        const f2 sq = st[r] * st[r];
        w[r] = sq[0] + sq[1];
    }
    #pragma unroll
    for (int bit = 1; bit < 16; bit <<= 1) {
        #pragma unroll
        for (int j = 0; j < 16; ++j) {
            if (!(j & bit)) {
                const float a = w[j], c = w[j | bit];
                w[j] = a + c; w[j | bit] = a - c;
            }
        }
    }
    // w[t] = sum_r (-1)^{popc(r&t)} p[r]

    float feats[NM];
    #pragma unroll
    for (int f = 0; f < NM; ++f) {
        const unsigned M = (f < NQ) ? TB.row[NLAY][f]
                                    : (TB.row[NLAY][f - NQ] ^ TB.row[NLAY][(f - NQ + 1) % NQ]);
        const unsigned Mlane = (M >> 4) & 63u;
        const int Mr = (int)(M & 15u);
        const float s = w[Mr];
        const int lsgn = __popc((unsigned)lane & Mlane) & 1;
        feats[f] = lsgn ? -s : s;
    }
    // reduction across all 64 lanes over basis masks {1,2,7,8,16,32}
    #pragma unroll
    for (int f = 0; f < NM; ++f) {
        float v = feats[f];
        v += dppf<0xB1>(v);    // ^1
        v += dppf<0x4E>(v);    // ^2
        v += dppf<0x141>(v);   // ^7
        v += dppf<0x128>(v);   // ^8
        v = redfold16(v);      // ^16
        v = redfold32(v);      // ^32
        feats[f] = v;
    }

    // ---- MLP head: lanes l and l+32 redundantly compute hidden unit l&31;
    //      the full-wave sum double-counts, so scale by 0.5 (exact).
    const int hl = lane & 31;
    float part;
    {
        float acc = b1[hl];
        #pragma unroll
        for (int mm = 0; mm < NM; ++mm) acc = fmaf(feats[mm], W1[hl * NM + mm], acc);
        const float sg = 1.f / (1.f + __expf(-acc));
        part = acc * sg * W2[hl];
    }
    part += dppf<0xB1>(part);
    part += dppf<0x4E>(part);
    part += dppf<0x141>(part);
    part += dppf<0x128>(part);
    part = redfold16(part);
    part = redfold32(part);
    if (lane == 0) out[b] = fmaf(0.5f, part, b2[0]);
}

extern "C" void kernel_launch(void* const* d_in, const int* in_sizes, int n_in,
                              void* d_out, int out_size, void* d_ws, size_t ws_size,
                              hipStream_t stream) {
    (void)in_sizes; (void)n_in; (void)out_size; (void)d_ws; (void)ws_size;
    const float* theta = (const float*)d_in[0];
    const float* rotw  = (const float*)d_in[1];
    const float* esc   = (const float*)d_in[2];
    const float* ebi   = (const float*)d_in[3];
    const float* W1    = (const float*)d_in[4];
    const float* b1    = (const float*)d_in[5];
    const float* W2    = (const float*)d_in[6];
    const float* b2    = (const float*)d_in[7];
    float* out = (float*)d_out;

    qrh_kernel<<<BATCH / 4, 256, 0, stream>>>(theta, rotw, esc, ebi, W1, b1, W2, b2, out);
}